// Round 6
// baseline (30398.447 us; speedup 1.0000x reference)
//
#include <hip/hip_runtime.h>
#include <math.h>

// LSTMCharTagger: char biLSTM (both dirs scan forward, batch 8192, T=16)
// -> gather last char -> word biLSTM (batch 1, S=8192 sequential) -> logits -> log_softmax.
// R6: word_scan v6 — f32 W streamed from L2 *before* the poll each step (loads
// pinned by the poll asm's memory clobber, latency hidden under the handshake),
// double-buffered LDS h (ONE barrier/step), in-wave gate gather + cell,
// dwordx4 sc0sc1 data-as-flag poll with __any-uniform exit + s_sleep backoff.

#define SW 8192
#define TC 16
#define ECD 64
#define HCD 128
#define DWD 300
#define HWD 256
#define DIND 556
#define NTAGS 50
#define SENT 0x40000000u   // 2.0f bit pattern; |h| < 1 so unreachable

typedef float f32x4 __attribute__((ext_vector_type(4)));

__device__ __forceinline__ float sigf(float x) { return 1.f / (1.f + expf(-x)); }

#define BM 64
#define BN 64
#define BK 16

// C[M,N] = A1@W1^T (+ A2@W2^T) + bias.  A1 rows optionally gathered via idx1.
__global__ __launch_bounds__(256) void gemm2(
    const float* __restrict__ A1, int lda1, const int* __restrict__ idx1,
    const float* __restrict__ W1, int ldw1, int K1,
    const float* __restrict__ A2, int lda2,
    const float* __restrict__ W2, int ldw2, int K2,
    const float* __restrict__ bias, float* __restrict__ C, int N, int ldc)
{
    __shared__ float As[BK][BM + 4];
    __shared__ float Ws[BK][BN + 4];
    const int tid = threadIdx.x;
    const int m0 = blockIdx.y * BM;
    const int n0 = blockIdx.x * BN;
    const int tx = tid & 15, ty = tid >> 4;
    const int lr = tid >> 2;
    const int lk4 = (tid & 3) << 2;

    float acc[4][4] = {};

    for (int part = 0; part < 2; ++part) {
        const int K = part ? K2 : K1;
        if (K == 0) continue;
        const float* A = part ? A2 : A1;
        const float* W = part ? W2 : W1;
        const int* idx = part ? (const int*)nullptr : idx1;
        const int lda = part ? lda2 : lda1;
        const int ldw = part ? ldw2 : ldw1;
        const int arow = idx ? idx[m0 + lr] : (m0 + lr);
        const float* Ab = A + (size_t)arow * lda;
        const int wrow = n0 + lr;
        const bool wv = wrow < N;
        const float* Wb = W + (size_t)(wv ? wrow : 0) * ldw;
        for (int k0 = 0; k0 < K; k0 += BK) {
            const int k = k0 + lk4;
            float4 av, bv;
            if (k + 3 < K) {
                av = *(const float4*)(Ab + k);
            } else {
                av.x = (k + 0 < K) ? Ab[k + 0] : 0.f;
                av.y = (k + 1 < K) ? Ab[k + 1] : 0.f;
                av.z = (k + 2 < K) ? Ab[k + 2] : 0.f;
                av.w = (k + 3 < K) ? Ab[k + 3] : 0.f;
            }
            if (wv && (k + 3 < K)) {
                bv = *(const float4*)(Wb + k);
            } else if (wv) {
                bv.x = (k + 0 < K) ? Wb[k + 0] : 0.f;
                bv.y = (k + 1 < K) ? Wb[k + 1] : 0.f;
                bv.z = (k + 2 < K) ? Wb[k + 2] : 0.f;
                bv.w = (k + 3 < K) ? Wb[k + 3] : 0.f;
            } else {
                bv.x = bv.y = bv.z = bv.w = 0.f;
            }
            As[lk4 + 0][lr] = av.x;
            As[lk4 + 1][lr] = av.y;
            As[lk4 + 2][lr] = av.z;
            As[lk4 + 3][lr] = av.w;
            Ws[lk4 + 0][lr] = bv.x;
            Ws[lk4 + 1][lr] = bv.y;
            Ws[lk4 + 2][lr] = bv.z;
            Ws[lk4 + 3][lr] = bv.w;
            __syncthreads();
#pragma unroll
            for (int kk = 0; kk < BK; ++kk) {
                const float4 a = *(const float4*)&As[kk][ty << 2];
                const float4 b = *(const float4*)&Ws[kk][tx << 2];
                acc[0][0] += a.x * b.x; acc[0][1] += a.x * b.y; acc[0][2] += a.x * b.z; acc[0][3] += a.x * b.w;
                acc[1][0] += a.y * b.x; acc[1][1] += a.y * b.y; acc[1][2] += a.y * b.z; acc[1][3] += a.y * b.w;
                acc[2][0] += a.z * b.x; acc[2][1] += a.z * b.y; acc[2][2] += a.z * b.z; acc[2][3] += a.z * b.w;
                acc[3][0] += a.w * b.x; acc[3][1] += a.w * b.y; acc[3][2] += a.w * b.z; acc[3][3] += a.w * b.w;
            }
            __syncthreads();
        }
    }
#pragma unroll
    for (int i = 0; i < 4; ++i) {
        const int m = m0 + (ty << 2) + i;
#pragma unroll
        for (int j = 0; j < 4; ++j) {
            const int n = n0 + (tx << 2) + j;
            if (n < N) C[(size_t)m * ldc + n] = acc[i][j] + (bias ? bias[n] : 0.f);
        }
    }
}

__global__ __launch_bounds__(256) void build_cidx(const int* __restrict__ char_ix,
                                                  int* __restrict__ cidx)
{
    const int id = blockIdx.x * 256 + threadIdx.x;   // t*SW + s
    const int t = id >> 13, s = id & (SW - 1);
    cidx[id] = char_ix[s * TC + t];
}

// gates [SW][512] (i,f,g,o x128); updates c,h [SW][128];
// o_out: write h at row stride 256 (or null); crepr: write h where char_len-1==t (or null).
__global__ __launch_bounds__(256) void lstm_cell_char(
    const float* __restrict__ gates, float* __restrict__ c, float* __restrict__ h,
    float* __restrict__ o_out, float* __restrict__ crepr,
    const int* __restrict__ char_len, int t)
{
    const int id = blockIdx.x * 256 + threadIdx.x;
    const int s = id >> 7, j = id & (HCD - 1);
    const float* g = gates + (size_t)s * 512;
    const float gi = g[j], gf = g[HCD + j], gg = g[2 * HCD + j], go = g[3 * HCD + j];
    const float cn = sigf(gf) * c[id] + sigf(gi) * tanhf(gg);
    const float hn = sigf(go) * tanhf(cn);
    c[id] = cn;
    h[id] = hn;
    if (o_out) o_out[(size_t)s * 256 + j] = hn;
    if (crepr && (char_len[s] - 1 == t)) crepr[(size_t)s * 256 + j] = hn;
}

__global__ __launch_bounds__(256) void fill_sentinel(float4* __restrict__ a, int n4)
{
    const int i = blockIdx.x * 256 + threadIdx.x;
    if (i < n4) a[i] = float4{2.f, 2.f, 2.f, 2.f};
}

// Word-LSTM scan v6. Grid = 32 blocks x 256 thr: d = blk>>4, bb = blk&15.
// Block owns 16 h-indices (cols bb*16..bb*16+16) -> 64 gate rows.
// Thread tid = 4r+cg, r = 4*jj+g: row (g*256 + bb*16 + jj), cols [cg*64, cg*64+64).
// Per step: issue 16 dwordx4 W loads (L2 stream, hidden under poll) -> wave0
// polls h via dwordx4 sc0sc1 (data-as-flag, sentinel 2.0f, s_sleep backoff) ->
// ds-write to double-buffered hl -> ONE barrier -> dot + shfl reduce ->
// activation on cg0 lanes -> in-wave gather (3 shfl) -> cell on l%16==0 lanes ->
// coalesced 16B/wave h store (sc0 sc1).
__global__ __launch_bounds__(256, 1) void word_scan(
    const float* __restrict__ G,     // [2][SW][1024] precomputed x@Wih^T + b
    const float* __restrict__ Whh,   // [2][1024][256] f32
    float* __restrict__ out)         // [SW][512]; fwd cols 0..255, bwd 256..511; sentinel-filled
{
    const int d = blockIdx.x >> 4;
    const int bb = blockIdx.x & 15;
    const int tid = threadIdx.x;
    const int l = tid & 63;
    const int wave = tid >> 6;
    const int r = tid >> 2;                  // 0..63
    const int cg = tid & 3;                  // k col group
    const int jj = r >> 2;                   // 0..15: h index within block
    const int g = r & 3;                     // gate (varies every 4 lanes)
    const int grow = (g << 8) + (bb << 4) + jj;

    __shared__ __align__(16) float hl[2][4 * 68];  // double-buffered, cg slices stride 68

    const float* wrow = Whh + ((size_t)d << 18) + (size_t)grow * 256 + (cg << 6);
    const float* Gd = G + ((size_t)d * SW * 1024);
    const int dcol = d << 8;
    const int tstart = d ? (SW - 1) : 0;
    const int tstep = d ? -1 : 1;
    float creg = 0.f;

    float gval = 0.f;
    if (cg == 0) gval = Gd[(size_t)tstart * 1024 + grow];

    for (int it = 0; it < SW; ++it) {
        const int t = tstart + tstep * it;
        float* hb = &hl[it & 1][0];

        // 1) W loads: issued before the poll (poll asm's memory clobber pins
        //    them here); they complete from L2 during the handshake.
        f32x4 wv[16];
#pragma unroll
        for (int i = 0; i < 16; ++i) wv[i] = ((const f32x4*)wrow)[i];

        // 2) handshake: wave0 polls previous h (data-as-flag)
        if (wave == 0) {
            f32x4 hv;
            if (it) {
                const int tp = t - tstep;
                const float* hp = out + (size_t)tp * 512 + dcol + (l << 2);
                for (;;) {
                    asm volatile("global_load_dwordx4 %0, %1, off sc0 sc1\n\t"
                                 "s_waitcnt vmcnt(0)"
                                 : "=v"(hv) : "v"(hp) : "memory");
                    const unsigned* u = (const unsigned*)&hv;
                    const bool bad = (u[0] == SENT) | (u[1] == SENT) |
                                     (u[2] == SENT) | (u[3] == SENT);
                    if (!__any(bad)) break;
                    __builtin_amdgcn_s_sleep(1);
                }
            } else {
                hv = f32x4{0.f, 0.f, 0.f, 0.f};
            }
            *(f32x4*)&hb[(l >> 4) * 68 + ((l & 15) << 2)] = hv;
        }
        __syncthreads();                      // the ONLY barrier per step

        // 3) dot: 16 broadcast b128 LDS reads x FMA against streamed W
        const f32x4* hp4 = (const f32x4*)&hb[cg * 68];
        float a0 = 0.f, a1 = 0.f, a2 = 0.f, a3 = 0.f;
#pragma unroll
        for (int i = 0; i < 16; ++i) {
            const f32x4 h4 = hp4[i];
            a0 = fmaf(wv[i][0], h4[0], a0);
            a1 = fmaf(wv[i][1], h4[1], a1);
            a2 = fmaf(wv[i][2], h4[2], a2);
            a3 = fmaf(wv[i][3], h4[3], a3);
        }
        float s = (a0 + a1) + (a2 + a3);
        s += __shfl_xor(s, 1);
        s += __shfl_xor(s, 2);
        s += gval;                            // gval==0 on cg!=0 lanes (their s unused)

        // activation: tanh(x) = 2*sig(2x)-1 -> single exp path, light predication
        const float xx = (g == 2) ? (s + s) : s;
        const float sg = 1.f / (1.f + expf(-xx));
        const float act = (g == 2) ? (2.f * sg - 1.f) : sg;

        // 4) in-wave gate gather (group of 16 lanes holds all 4 gates of one j)
        const int gb = l & 48;
        const float af = __shfl(act, gb + 4);
        const float ag = __shfl(act, gb + 8);
        const float ao = __shfl(act, gb + 12);
        if ((l & 15) == 0) {                  // cell lanes: act == sig(i)
            creg = af * creg + act * ag;
            const float hn = ao * tanhf(creg);
            const int j = (wave << 2) + (l >> 4);
            float* dst = out + (size_t)t * 512 + dcol + (bb << 4) + j;
            asm volatile("global_store_dword %0, %1, off sc0 sc1"
                         :: "v"(dst), "v"(hn) : "memory");
        }

        // 5) G prefetch for next step (HBM latency hidden under next poll)
        if (cg == 0 && it + 1 < SW)
            gval = Gd[(size_t)(t + tstep) * 1024 + grow];
    }
}

__global__ __launch_bounds__(256) void logsoftmax50(const float* __restrict__ X,
                                                    float* __restrict__ Y)
{
    const int gw = (blockIdx.x * 256 + threadIdx.x) >> 6;
    const int lane = threadIdx.x & 63;
    if (gw >= SW) return;
    const float v = (lane < NTAGS) ? X[(size_t)gw * NTAGS + lane] : -3.4e38f;
    float m = v;
#pragma unroll
    for (int o = 32; o; o >>= 1) m = fmaxf(m, __shfl_xor(m, o));
    const float e = (lane < NTAGS) ? expf(v - m) : 0.f;
    float sum = e;
#pragma unroll
    for (int o = 32; o; o >>= 1) sum += __shfl_xor(sum, o);
    if (lane < NTAGS) Y[(size_t)gw * NTAGS + lane] = v - m - logf(sum);
}

extern "C" void kernel_launch(void* const* d_in, const int* in_sizes, int n_in,
                              void* d_out, int out_size, void* d_ws, size_t ws_size,
                              hipStream_t stream)
{
    const int* word_ix  = (const int*)d_in[0];
    const int* char_ix  = (const int*)d_in[1];
    const int* char_len = (const int*)d_in[2];
    const float* word_emb = (const float*)d_in[3];
    const float* char_emb = (const float*)d_in[4];
    const float* cW_ih0 = (const float*)d_in[5];
    const float* cW_hh0 = (const float*)d_in[6];
    const float* cb0    = (const float*)d_in[7];
    const float* cW_ih1 = (const float*)d_in[8];
    const float* cW_hh1 = (const float*)d_in[9];
    const float* cb1    = (const float*)d_in[10];
    const float* wW_ih0 = (const float*)d_in[11];
    const float* wW_hh0 = (const float*)d_in[12];
    const float* wb0    = (const float*)d_in[13];
    const float* wW_ih1 = (const float*)d_in[14];
    const float* wW_hh1 = (const float*)d_in[15];
    const float* wb1    = (const float*)d_in[16];
    const float* out_W  = (const float*)d_in[17];
    const float* out_b  = (const float*)d_in[18];
    float* Y = (float*)d_out;
    (void)in_sizes; (void)n_in; (void)out_size; (void)ws_size;

    char* p = (char*)d_ws;
    auto alloc = [&](size_t bytes) { char* q = p; p += (bytes + 255) & ~(size_t)255; return q; };
    float* ch_h  = (float*)alloc(4ull * SW * HCD * 4);         // [layer*2+dir][SW][HCD]
    float* ch_c  = (float*)alloc(4ull * SW * HCD * 4);
    const size_t zbytes = (size_t)(p - (char*)d_ws);           // zero: ch_h + ch_c
    float* gates = (float*)alloc(2ull * SW * 512 * 4);         // per-dir char gates / logits tmp
    float* o0s   = (float*)alloc((size_t)SW * 256 * 4);        // layer-0 output, current t only
    float* crepr = (float*)alloc((size_t)SW * 256 * 4);
    float* wG    = (float*)alloc(2ull * SW * 1024 * 4);        // word gate inputs (reused L0->L1)
    float* wo0   = (float*)alloc((size_t)SW * 512 * 4);
    float* wo1   = (float*)alloc((size_t)SW * 512 * 4);
    int*   cidx  = (int*)  alloc((size_t)TC * SW * 4);

    hipMemsetAsync(d_ws, 0, zbytes, stream);
    fill_sentinel<<<(SW * 512 / 4 + 255) / 256, 256, 0, stream>>>((float4*)wo0, SW * 512 / 4);
    fill_sentinel<<<(SW * 512 / 4 + 255) / 256, 256, 0, stream>>>((float4*)wo1, SW * 512 / 4);
    build_cidx<<<TC * SW / 256, 256, 0, stream>>>(char_ix, cidx);

    // ---- char biLSTM: L0 and L1 interleaved per timestep (o0s is one-step ring) ----
    for (int t = 0; t < TC; ++t) {
        for (int d = 0; d < 2; ++d)
            gemm2<<<dim3(512 / BN, SW / BM), 256, 0, stream>>>(
                char_emb, ECD, cidx + t * SW, cW_ih0 + (size_t)d * 512 * ECD, ECD, ECD,
                ch_h + (size_t)d * SW * HCD, HCD, cW_hh0 + (size_t)d * 512 * HCD, HCD, HCD,
                cb0 + d * 512, gates + (size_t)d * SW * 512, 512, 512);
        for (int d = 0; d < 2; ++d)
            lstm_cell_char<<<SW * HCD / 256, 256, 0, stream>>>(
                gates + (size_t)d * SW * 512, ch_c + (size_t)d * SW * HCD,
                ch_h + (size_t)d * SW * HCD, o0s + d * HCD, nullptr, nullptr, t);
        for (int d = 0; d < 2; ++d)
            gemm2<<<dim3(512 / BN, SW / BM), 256, 0, stream>>>(
                o0s, 256, nullptr, cW_ih1 + (size_t)d * 512 * 256, 256, 256,
                ch_h + (size_t)(2 + d) * SW * HCD, HCD, cW_hh1 + (size_t)d * 512 * HCD, HCD, HCD,
                cb1 + d * 512, gates + (size_t)d * SW * 512, 512, 512);
        for (int d = 0; d < 2; ++d)
            lstm_cell_char<<<SW * HCD / 256, 256, 0, stream>>>(
                gates + (size_t)d * SW * 512, ch_c + (size_t)(2 + d) * SW * HCD,
                ch_h + (size_t)(2 + d) * SW * HCD, nullptr, crepr + d * HCD, char_len, t);
    }

    // ---- word biLSTM layer 0 ----
    for (int d = 0; d < 2; ++d)
        gemm2<<<dim3(1024 / BN, SW / BM), 256, 0, stream>>>(
            word_emb, DWD, word_ix, wW_ih0 + (size_t)d * 1024 * DIND, DIND, DWD,
            crepr, 256, wW_ih0 + (size_t)d * 1024 * DIND + DWD, DIND, 256,
            wb0 + d * 1024, wG + (size_t)d * SW * 1024, 1024, 1024);
    word_scan<<<32, 256, 0, stream>>>(wG, wW_hh0, wo0);

    // ---- word biLSTM layer 1 ----
    for (int d = 0; d < 2; ++d)
        gemm2<<<dim3(1024 / BN, SW / BM), 256, 0, stream>>>(
            wo0, 512, nullptr, wW_ih1 + (size_t)d * 1024 * 512, 512, 512,
            nullptr, 0, nullptr, 0, 0,
            wb1 + d * 1024, wG + (size_t)d * SW * 1024, 1024, 1024);
    word_scan<<<32, 256, 0, stream>>>(wG, wW_hh1, wo1);

    // ---- logits + log_softmax ----
    gemm2<<<dim3(1, SW / BM), 256, 0, stream>>>(
        wo1, 512, nullptr, out_W, 512, 512,
        nullptr, 0, nullptr, 0, 0,
        out_b, gates, NTAGS, NTAGS);
    logsoftmax50<<<SW * 64 / 256, 256, 0, stream>>>(gates, Y);
}